// Round 1
// baseline (876.782 us; speedup 1.0000x reference)
//
#include <hip/hip_runtime.h>
#include <hip/hip_bf16.h>

typedef __attribute__((ext_vector_type(8))) short short8;
typedef __attribute__((ext_vector_type(4))) float f32x4;

#define GM 32768   // B*H*W
#define DH 32      // head dim

__device__ __forceinline__ ushort f2bf(float f) {
  unsigned int u = __float_as_uint(f);
  u += 0x7FFFu + ((u >> 16) & 1u);   // round-to-nearest-even
  return (ushort)(u >> 16);
}

// ---- cast fp32 -> bf16, 4 elems/thread ----
__global__ __launch_bounds__(256) void cast_bf16(const float* __restrict__ in,
                                                 ushort* __restrict__ out, int n) {
  int idx = (blockIdx.x * 256 + threadIdx.x) * 4;
  if (idx + 3 < n) {
    float4 t = *(const float4*)(in + idx);
    ushort4 o;
    o.x = f2bf(t.x); o.y = f2bf(t.y); o.z = f2bf(t.z); o.w = f2bf(t.w);
    *(ushort4*)(out + idx) = o;
  }
}

// ---- bf16 MFMA GEMM: C[M,N] = A[M,K] * Bt[N,K]^T (+bias) ----
// MODE 0: qkv epilogue — scale cols<256 by `scale`, scatter to [sel][head][M][32] fp32
// MODE 1: proj epilogue — plain row-major fp32 out + bias
template<int MODE>
__global__ __launch_bounds__(256) void gemm_bt(
    const ushort* __restrict__ A, const ushort* __restrict__ Bt,
    float* __restrict__ C, const float* __restrict__ bias,
    int M, int N, int K, float scale) {
  const int BM = 128, BN = 128, BK = 64;
  __shared__ int4 sA4[BM * BK / 8];   // 16 KB, 16B-chunk XOR swizzled
  __shared__ int4 sB4[BN * BK / 8];   // 16 KB

  int tid = threadIdx.x;
  int lane = tid & 63, wid = tid >> 6;
  int wm = (wid >> 1) * 64, wn = (wid & 1) * 64;   // wave 2x2 -> 64x64 subtile
  int bm = blockIdx.y, bn = blockIdx.x;
  int lo = lane & 15, hi = lane >> 4;

  f32x4 acc[4][4] = {};

  for (int kt = 0; kt < K; kt += BK) {
    int4 ra[4], rb[4];
#pragma unroll
    for (int i = 0; i < 4; ++i) {
      int cid = tid + i * 256;          // 1024 16B chunks per tile
      int r = cid >> 3, c = cid & 7;
      ra[i] = *(const int4*)(A  + (size_t)(bm * BM + r) * K + kt + c * 8);
      rb[i] = *(const int4*)(Bt + (size_t)(bn * BN + r) * K + kt + c * 8);
    }
    __syncthreads();                    // previous iter's ds_reads done
#pragma unroll
    for (int i = 0; i < 4; ++i) {
      int cid = tid + i * 256;
      int r = cid >> 3, c = cid & 7;
      sA4[r * 8 + (c ^ (r & 7))] = ra[i];
      sB4[r * 8 + (c ^ (r & 7))] = rb[i];
    }
    __syncthreads();
#pragma unroll
    for (int ks = 0; ks < 2; ++ks) {
      short8 af[4], bfr[4];
#pragma unroll
      for (int mi = 0; mi < 4; ++mi) {
        int r = wm + mi * 16 + lo;
        int c = ks * 4 + hi;
        af[mi] = ((const short8*)sA4)[r * 8 + (c ^ (r & 7))];
      }
#pragma unroll
      for (int nj = 0; nj < 4; ++nj) {
        int r = wn + nj * 16 + lo;
        int c = ks * 4 + hi;
        bfr[nj] = ((const short8*)sB4)[r * 8 + (c ^ (r & 7))];
      }
#pragma unroll
      for (int mi = 0; mi < 4; ++mi)
#pragma unroll
        for (int nj = 0; nj < 4; ++nj)
          acc[mi][nj] = __builtin_amdgcn_mfma_f32_16x16x32_bf16(
              af[mi], bfr[nj], acc[mi][nj], 0, 0, 0);
    }
  }

#pragma unroll
  for (int mi = 0; mi < 4; ++mi) {
#pragma unroll
    for (int nj = 0; nj < 4; ++nj) {
#pragma unroll
      for (int r = 0; r < 4; ++r) {
        int row = bm * BM + wm + mi * 16 + hi * 4 + r;   // C/D: col=lane&15, row=(lane>>4)*4+reg
        int col = bn * BN + wn + nj * 16 + lo;
        float v = acc[mi][nj][r] + bias[col];
        if (MODE == 0) {
          if (col < 256) v *= scale;                     // q pre-scale
          int sel = col >> 8, h = (col >> 5) & 7, d = col & 31;
          C[((size_t)(sel * 8 + h) * M + row) * DH + d] = v;
        } else {
          C[(size_t)row * N + col] = v;
        }
      }
    }
  }
}

// ---- neighborhood attention, one thread per (b, head, i, j), fp32, no-max softmax ----
template<int KS>
__device__ __forceinline__ void natt_body(const float* __restrict__ qkv,
                                          const float* __restrict__ rpb,
                                          ushort* __restrict__ y,
                                          int gid, int hoff) {
  const int L = 64, NHF = KS / 2, BWD = 2 * KS - 1;
  int j = threadIdx.x;                     // 0..63
  int i = (gid & 15) * 4 + threadIdx.y;    // 0..63
  int hl = (gid >> 4) & 3;
  int b = gid >> 6;
  int h = hoff + hl;

  int wi = (i < NHF) ? 0 : ((i >= L - NHF) ? (L - KS) : (i - NHF));
  int pi = NHF + ((i < NHF) ? (NHF - i) : 0) + ((i >= L - NHF) ? (L - 1 - NHF - i) : 0);
  int wj = (j < NHF) ? 0 : ((j >= L - NHF) ? (L - KS) : (j - NHF));
  int pj = NHF + ((j < NHF) ? (NHF - j) : 0) + ((j >= L - NHF) ? (L - 1 - NHF - j) : 0);

  size_t pos = (size_t)(b * 64 + i) * 64 + j;
  const float* qp = qkv + ((size_t)h * GM + pos) * DH;
  const float* kb = qkv + ((size_t)(8 + h) * GM + (size_t)b * 4096) * DH;
  const float* vb = qkv + ((size_t)(16 + h) * GM + (size_t)b * 4096) * DH;
  const float* bias = rpb + hl * BWD * BWD + pi * BWD + pj;

  float q[DH];
#pragma unroll
  for (int d4 = 0; d4 < 8; ++d4) {
    float4 t = ((const float4*)qp)[d4];
    q[d4*4+0] = t.x; q[d4*4+1] = t.y; q[d4*4+2] = t.z; q[d4*4+3] = t.w;
  }
  float acc[DH] = {};
  float lsum = 0.f;
  for (int ki = 0; ki < KS; ++ki) {
    const float* kr = kb + (size_t)((wi + ki) * 64 + wj) * DH;
    const float* vr = vb + (size_t)((wi + ki) * 64 + wj) * DH;
    const float* br = bias + ki * BWD;
    for (int kj = 0; kj < KS; ++kj) {
      const float* kp = kr + kj * DH;
      float s = 0.f;
#pragma unroll
      for (int d4 = 0; d4 < 8; ++d4) {
        float4 t = ((const float4*)kp)[d4];
        s += q[d4*4+0]*t.x + q[d4*4+1]*t.y + q[d4*4+2]*t.z + q[d4*4+3]*t.w;
      }
      float p = __expf(s + br[kj]);   // logits bounded (~|3|) -> no max subtraction needed
      lsum += p;
      const float* vp = vr + kj * DH;
#pragma unroll
      for (int d4 = 0; d4 < 8; ++d4) {
        float4 t = ((const float4*)vp)[d4];
        acc[d4*4+0] += p*t.x; acc[d4*4+1] += p*t.y; acc[d4*4+2] += p*t.z; acc[d4*4+3] += p*t.w;
      }
    }
  }
  float inv = 1.f / lsum;
  unsigned int pw[DH/2];
#pragma unroll
  for (int d2 = 0; d2 < DH/2; ++d2)
    pw[d2] = (unsigned int)f2bf(acc[2*d2] * inv) |
             ((unsigned int)f2bf(acc[2*d2+1] * inv) << 16);
  uint4* yp4 = (uint4*)(y + pos * 256 + h * DH);
#pragma unroll
  for (int c = 0; c < 4; ++c)
    yp4[c] = make_uint4(pw[4*c], pw[4*c+1], pw[4*c+2], pw[4*c+3]);
}

__global__ __launch_bounds__(256) void natt_all(const float* __restrict__ qkv,
    const float* __restrict__ rpb0, const float* __restrict__ rpb1,
    ushort* __restrict__ y) {
  int gid = blockIdx.x;
  if (gid < 512) natt_body<7>(qkv, rpb0, y, gid, 0);
  else           natt_body<13>(qkv, rpb1, y, gid - 512, 4);
}

extern "C" void kernel_launch(void* const* d_in, const int* in_sizes, int n_in,
                              void* d_out, int out_size, void* d_ws, size_t ws_size,
                              hipStream_t stream) {
  const float* x      = (const float*)d_in[0];
  const float* w_qkv  = (const float*)d_in[1];
  const float* b_qkv  = (const float*)d_in[2];
  const float* rpb0   = (const float*)d_in[3];
  const float* rpb1   = (const float*)d_in[4];
  const float* w_proj = (const float*)d_in[5];
  const float* b_proj = (const float*)d_in[6];
  float* out = (float*)d_out;

  char* ws = (char*)d_ws;
  ushort* xb  = (ushort*)(ws);                                          // 16 MB
  ushort* wqb = (ushort*)(ws + 16777216);                               // 384 KB
  ushort* wpb = (ushort*)(ws + 16777216 + 393216);                      // 128 KB
  float*  qkv = (float*)(ws + 16777216 + 393216 + 131072);              // 96 MB: [3][8][32768][32]
  ushort* yb  = (ushort*)(ws + 16777216 + 393216 + 131072 + 100663296); // 16 MB: [32768][256]

  cast_bf16<<<8192, 256, 0, stream>>>(x, xb, 8388608);
  cast_bf16<<<192, 256, 0, stream>>>(w_qkv, wqb, 196608);
  cast_bf16<<<64, 256, 0, stream>>>(w_proj, wpb, 65536);
  gemm_bt<0><<<dim3(6, 256), 256, 0, stream>>>(xb, wqb, qkv, b_qkv,
                                               32768, 768, 256, 0.17677669529663687f);
  natt_all<<<1024, dim3(64, 4), 0, stream>>>(qkv, rpb0, rpb1, yb);
  gemm_bt<1><<<dim3(2, 256), 256, 0, stream>>>(yb, wpb, out, b_proj,
                                               32768, 256, 256, 1.0f);
}